// Round 3
// baseline (218.392 us; speedup 1.0000x reference)
//
#include <hip/hip_runtime.h>

#define BB 8
#define NN 4096
#define LL 4096
#define CC 256

typedef short bf16x8 __attribute__((ext_vector_type(8)));
typedef _Float16 f16x8 __attribute__((ext_vector_type(8)));
typedef __fp16 hf16x2 __attribute__((ext_vector_type(2)));  // cvt_pkrtz return type
typedef float f32x4 __attribute__((ext_vector_type(4)));

__device__ __forceinline__ float bf2f(short s) {
  union { unsigned u; float f; } v;
  v.u = ((unsigned)(unsigned short)s) << 16;
  return v.f;
}
__device__ __forceinline__ short f2bf(float f) {
  union { float f; unsigned u; } v; v.f = f;
  unsigned r = v.u + 0x7fffu + ((v.u >> 16) & 1u);
  return (short)(r >> 16);
}

// Input dtype probe: f32 normal data -> u32 exponent byte in [100,140] for
// essentially every word; packed bf16 pairs -> exp byte in {0..5}u{236..255}
// (high short's exp[6:0]:mant[6] bits), never in [100,140]. Uniform across
// the workgroup; 64 L2-hit loads.
__device__ __forceinline__ int detect_f32(const void* g) {
  const unsigned* u = (const unsigned*)g;
  int cnt = 0;
  #pragma unroll
  for (int i = 0; i < 64; ++i) {
    unsigned e = (u[i] >> 23) & 0xffu;
    cnt += (e >= 100u && e <= 140u) ? 1 : 0;
  }
  return cnt >= 32;
}

// Load one element as float from an f32-or-bf16 buffer.
__device__ __forceinline__ float ldel(const void* p, size_t i, int f32m) {
  return f32m ? ((const float*)p)[i] : bf2f(((const short*)p)[i]);
}
// Load 8 consecutive elements as a bf16x8 MFMA fragment.
__device__ __forceinline__ bf16x8 ld8bf(const void* p, size_t i, int f32m) {
  if (f32m) {
    const float* fp = (const float*)p + i;
    float4 a = *(const float4*)fp;
    float4 b = *(const float4*)(fp + 4);
    bf16x8 r;
    r[0] = f2bf(a.x); r[1] = f2bf(a.y); r[2] = f2bf(a.z); r[3] = f2bf(a.w);
    r[4] = f2bf(b.x); r[5] = f2bf(b.y); r[6] = f2bf(b.z); r[7] = f2bf(b.w);
    return r;
  }
  return *(const bf16x8*)((const short*)p + i);
}

// ---------------------------------------------------------------------------
// Kernel A: projections.
//   blocks 0..511   : K/V  (per block: one b, 64 l; per wave: 16 l)
//       Kt[b][l][o] = (Wk@img + bk)[o][l] * log2(e)/sqrt(32)   (bf16)
//       Vt[b][l][o] = (Wv@img + bv)[o][l]                      (f16)
//   blocks 512..1023: Q    (per block: one b, 64 n; per wave: 16 n)
//       Qb[b][n][o] = (graph@Wq^T + bq)[n][o]                  (bf16)
// ---------------------------------------------------------------------------
__global__ __launch_bounds__(256) void ka_proj(
    const void* __restrict__ graph, const void* __restrict__ img,
    const void* __restrict__ Wq, const void* __restrict__ bq,
    const void* __restrict__ Wk, const void* __restrict__ bk,
    const void* __restrict__ Wv, const void* __restrict__ bv,
    short* __restrict__ Qb, short* __restrict__ Kt, _Float16* __restrict__ Vt)
{
  const int f32m = detect_f32(graph);
  const int tid = threadIdx.x;
  const int w = tid >> 6, lane = tid & 63, lo = lane & 15, q = lane >> 4;
  const int bid = blockIdx.x;
  if (bid < 512) {
    const int b = bid >> 6;
    const int lt = ((bid & 63) << 6) + (w << 4);
    f32x4 aK0 = {0,0,0,0}, aK1 = {0,0,0,0}, aV0 = {0,0,0,0}, aV1 = {0,0,0,0};
    const size_t ibase = (size_t)b * CC * LL + lt + lo;
    #pragma unroll
    for (int cs = 0; cs < 8; ++cs) {
      const int c0 = cs * 32 + q * 8;
      bf16x8 bi;
      #pragma unroll
      for (int j = 0; j < 8; ++j)
        bi[j] = f2bf(ldel(img, ibase + (size_t)(c0 + j) * LL, f32m));
      bf16x8 wk0 = ld8bf(Wk, (size_t)lo * CC + c0, f32m);
      bf16x8 wk1 = ld8bf(Wk, (size_t)(lo + 16) * CC + c0, f32m);
      bf16x8 wv0 = ld8bf(Wv, (size_t)lo * CC + c0, f32m);
      bf16x8 wv1 = ld8bf(Wv, (size_t)(lo + 16) * CC + c0, f32m);
      aK0 = __builtin_amdgcn_mfma_f32_16x16x32_bf16(wk0, bi, aK0, 0, 0, 0);
      aK1 = __builtin_amdgcn_mfma_f32_16x16x32_bf16(wk1, bi, aK1, 0, 0, 0);
      aV0 = __builtin_amdgcn_mfma_f32_16x16x32_bf16(wv0, bi, aV0, 0, 0, 0);
      aV1 = __builtin_amdgcn_mfma_f32_16x16x32_bf16(wv1, bi, aV1, 0, 0, 0);
    }
    // fold 1/sqrt(32) * log2(e) into K so softmax exp becomes exp2
    const float kscale = 0.2550348663f;
    const size_t row = ((size_t)b * LL + lt + lo) * 32;
    short4 s0, s1;
    s0.x = f2bf((aK0[0] + ldel(bk, q * 4 + 0, f32m)) * kscale);
    s0.y = f2bf((aK0[1] + ldel(bk, q * 4 + 1, f32m)) * kscale);
    s0.z = f2bf((aK0[2] + ldel(bk, q * 4 + 2, f32m)) * kscale);
    s0.w = f2bf((aK0[3] + ldel(bk, q * 4 + 3, f32m)) * kscale);
    s1.x = f2bf((aK1[0] + ldel(bk, 16 + q * 4 + 0, f32m)) * kscale);
    s1.y = f2bf((aK1[1] + ldel(bk, 16 + q * 4 + 1, f32m)) * kscale);
    s1.z = f2bf((aK1[2] + ldel(bk, 16 + q * 4 + 2, f32m)) * kscale);
    s1.w = f2bf((aK1[3] + ldel(bk, 16 + q * 4 + 3, f32m)) * kscale);
    *(short4*)(Kt + row + q * 4) = s0;
    *(short4*)(Kt + row + 16 + q * 4) = s1;
    union { hf16x2 h[2]; uint2 u; } p0, p1;
    p0.h[0] = __builtin_amdgcn_cvt_pkrtz(aV0[0] + ldel(bv, q * 4 + 0, f32m),
                                         aV0[1] + ldel(bv, q * 4 + 1, f32m));
    p0.h[1] = __builtin_amdgcn_cvt_pkrtz(aV0[2] + ldel(bv, q * 4 + 2, f32m),
                                         aV0[3] + ldel(bv, q * 4 + 3, f32m));
    p1.h[0] = __builtin_amdgcn_cvt_pkrtz(aV1[0] + ldel(bv, 16 + q * 4 + 0, f32m),
                                         aV1[1] + ldel(bv, 16 + q * 4 + 1, f32m));
    p1.h[1] = __builtin_amdgcn_cvt_pkrtz(aV1[2] + ldel(bv, 16 + q * 4 + 2, f32m),
                                         aV1[3] + ldel(bv, 16 + q * 4 + 3, f32m));
    *(uint2*)(Vt + row + q * 4) = p0.u;
    *(uint2*)(Vt + row + 16 + q * 4) = p1.u;
  } else {
    const int t = bid - 512;
    const int b = t >> 6;
    const int nt = ((t & 63) << 6) + (w << 4);
    bf16x8 ag = ld8bf(graph, ((size_t)b * NN + nt + lo) * 32 + q * 8, f32m);
    bf16x8 w0 = ld8bf(Wq, (size_t)lo * 32 + q * 8, f32m);
    bf16x8 w1 = ld8bf(Wq, (size_t)(lo + 16) * 32 + q * 8, f32m);
    f32x4 z = {0,0,0,0};
    f32x4 a0 = __builtin_amdgcn_mfma_f32_16x16x32_bf16(ag, w0, z, 0, 0, 0);
    f32x4 a1 = __builtin_amdgcn_mfma_f32_16x16x32_bf16(ag, w1, z, 0, 0, 0);
    const float b0 = ldel(bq, lo, f32m), b1 = ldel(bq, lo + 16, f32m);
    #pragma unroll
    for (int r = 0; r < 4; ++r) {
      const size_t rowq = ((size_t)b * NN + nt + q * 4 + r) * 32;
      Qb[rowq + lo] = f2bf(a0[r] + b0);
      Qb[rowq + 16 + lo] = f2bf(a1[r] + b1);
    }
  }
}

// ---------------------------------------------------------------------------
// Kernel B: softmax denominators Z_l = sum_n exp2(S'[n][l]), then
// Vpp[b][o][l] = Vt[b][l][o] * (4096 / Z_l)  (f16).  Workspace-only I/O.
// ---------------------------------------------------------------------------
__global__ __launch_bounds__(256) void kb_z(
    const short* __restrict__ Qb, const short* __restrict__ Kt,
    const _Float16* __restrict__ Vt, _Float16* __restrict__ Vpp)
{
  __shared__ float zpart[4][64];
  __shared__ float zinv[64];
  const int tid = threadIdx.x;
  const int w = tid >> 6, lane = tid & 63, lo = lane & 15, q = lane >> 4;
  const int b = blockIdx.x >> 6;
  const int l0 = (blockIdx.x & 63) << 6;
  bf16x8 kf[4];
  #pragma unroll
  for (int f = 0; f < 4; ++f)
    kf[f] = *(const bf16x8*)(Kt + ((size_t)b * LL + l0 + f * 16 + lo) * 32 + q * 8);
  float za[4][4] = {{0}};
  const short* qbase = Qb + ((size_t)b * NN + w * 1024 + lo) * 32 + q * 8;
  for (int it = 0; it < 64; ++it) {
    bf16x8 qf = *(const bf16x8*)(qbase + it * 512);
    #pragma unroll
    for (int f = 0; f < 4; ++f) {
      f32x4 z = {0,0,0,0};
      f32x4 c = __builtin_amdgcn_mfma_f32_16x16x32_bf16(kf[f], qf, z, 0, 0, 0);
      #pragma unroll
      for (int r = 0; r < 4; ++r) za[f][r] += __builtin_exp2f(c[r]);
    }
  }
  #pragma unroll
  for (int m = 1; m < 16; m <<= 1)
    #pragma unroll
    for (int f = 0; f < 4; ++f)
      #pragma unroll
      for (int r = 0; r < 4; ++r)
        za[f][r] += __shfl_xor(za[f][r], m, 64);
  if (lo == 0) {
    #pragma unroll
    for (int f = 0; f < 4; ++f)
      #pragma unroll
      for (int r = 0; r < 4; ++r)
        zpart[w][f * 16 + q * 4 + r] = za[f][r];
  }
  __syncthreads();
  if (tid < 64) {
    const float z = zpart[0][tid] + zpart[1][tid] + zpart[2][tid] + zpart[3][tid];
    zinv[tid] = 4096.0f / z;   // 4096: keep f16 V'' away from subnormals
  }
  __syncthreads();
  {
    const int l = tid & 63, og = tid >> 6;
    const float inv = zinv[l];
    const f16x8 vv = *(const f16x8*)(Vt + ((size_t)b * LL + l0 + l) * 32 + og * 8);
    #pragma unroll
    for (int j = 0; j < 8; ++j) {
      const float sv = (float)vv[j] * inv;
      Vpp[((size_t)b * 32 + og * 8 + j) * LL + l0 + l] = (_Float16)sv;
    }
  }
}

// ---------------------------------------------------------------------------
// Kernel C: pass 2. Main loop is workspace-only; graph/Wc/bc/out touched only
// in the epilogue (dtype-adaptive there).
// ---------------------------------------------------------------------------
__global__ __launch_bounds__(256) void kc_attn(
    const short* __restrict__ Qb, const short* __restrict__ Kt,
    const _Float16* __restrict__ Vpp, const void* __restrict__ graph,
    const void* __restrict__ Wc, const void* __restrict__ bc,
    void* __restrict__ outv)
{
  __shared__ __align__(16) _Float16 P[4][32][72];   // per-wave [32 n][64 l]
  __shared__ __align__(16) float msgL[4][32][36];   // per-wave msg partial
  const int f32m = detect_f32(graph);
  const int tid = threadIdx.x;
  const int w = tid >> 6, lane = tid & 63, lo = lane & 15, q = lane >> 4;
  const int b = blockIdx.x >> 7;
  const int n0 = (blockIdx.x & 127) << 5;
  const bf16x8 qf0 = *(const bf16x8*)(Qb + ((size_t)b * NN + n0 + lo) * 32 + q * 8);
  const bf16x8 qf1 = *(const bf16x8*)(Qb + ((size_t)b * NN + n0 + 16 + lo) * 32 + q * 8);
  f32x4 m00 = {0,0,0,0}, m01 = {0,0,0,0}, m10 = {0,0,0,0}, m11 = {0,0,0,0};
  const short* ktb = Kt + (size_t)b * LL * 32 + lo * 32 + q * 8;
  const _Float16* vb0 = Vpp + ((size_t)b * 32 + lo) * LL;
  const _Float16* vb1 = vb0 + (size_t)16 * LL;
  for (int lc = w * 16; lc < w * 16 + 16; ++lc) {
    const int lbase = lc * 64;
    #pragma unroll
    for (int f = 0; f < 4; ++f) {
      bf16x8 kf = *(const bf16x8*)(ktb + (size_t)(lbase + f * 16) * 32);
      f32x4 z = {0,0,0,0};
      f32x4 c0 = __builtin_amdgcn_mfma_f32_16x16x32_bf16(kf, qf0, z, 0, 0, 0);
      f32x4 c1 = __builtin_amdgcn_mfma_f32_16x16x32_bf16(kf, qf1, z, 0, 0, 0);
      union { hf16x2 h[2]; uint2 u; } pk0, pk1;
      pk0.h[0] = __builtin_amdgcn_cvt_pkrtz(__builtin_exp2f(c0[0]), __builtin_exp2f(c0[1]));
      pk0.h[1] = __builtin_amdgcn_cvt_pkrtz(__builtin_exp2f(c0[2]), __builtin_exp2f(c0[3]));
      pk1.h[0] = __builtin_amdgcn_cvt_pkrtz(__builtin_exp2f(c1[0]), __builtin_exp2f(c1[1]));
      pk1.h[1] = __builtin_amdgcn_cvt_pkrtz(__builtin_exp2f(c1[2]), __builtin_exp2f(c1[3]));
      *(uint2*)&P[w][lo][f * 16 + q * 4] = pk0.u;
      *(uint2*)&P[w][16 + lo][f * 16 + q * 4] = pk1.u;
    }
    #pragma unroll
    for (int k = 0; k < 2; ++k) {
      f16x8 pa0 = *(const f16x8*)&P[w][lo][k * 32 + q * 8];
      f16x8 pa1 = *(const f16x8*)&P[w][16 + lo][k * 32 + q * 8];
      f16x8 v0 = *(const f16x8*)(vb0 + lbase + k * 32 + q * 8);
      f16x8 v1 = *(const f16x8*)(vb1 + lbase + k * 32 + q * 8);
      m00 = __builtin_amdgcn_mfma_f32_16x16x32_f16(pa0, v0, m00, 0, 0, 0);
      m01 = __builtin_amdgcn_mfma_f32_16x16x32_f16(pa0, v1, m01, 0, 0, 0);
      m10 = __builtin_amdgcn_mfma_f32_16x16x32_f16(pa1, v0, m10, 0, 0, 0);
      m11 = __builtin_amdgcn_mfma_f32_16x16x32_f16(pa1, v1, m11, 0, 0, 0);
    }
  }
  #pragma unroll
  for (int r = 0; r < 4; ++r) {
    msgL[w][q * 4 + r][lo] = m00[r];
    msgL[w][q * 4 + r][16 + lo] = m01[r];
    msgL[w][16 + q * 4 + r][lo] = m10[r];
    msgL[w][16 + q * 4 + r][16 + lo] = m11[r];
  }
  __syncthreads();
  // epilogue: out[n][o] = graph + bc[o] + sum_c Wc[o][c]*msg[n][c] / 4096
  const int o = lane & 31, nh = lane >> 5;
  float wcr[32];
  #pragma unroll
  for (int c4 = 0; c4 < 8; ++c4)
    #pragma unroll
    for (int jj = 0; jj < 4; ++jj)
      wcr[c4 * 4 + jj] = ldel(Wc, o * 32 + c4 * 4 + jj, f32m) * (1.0f / 4096.0f);
  const float bcv = ldel(bc, o, f32m);
  #pragma unroll
  for (int rr = 0; rr < 4; ++rr) {
    const int nl = w * 8 + nh * 4 + rr;
    f32x4 s = {0,0,0,0};
    #pragma unroll
    for (int cc = 0; cc < 8; ++cc) {
      f32x4 ma = *(const f32x4*)&msgL[0][nl][cc * 4];
      f32x4 mb = *(const f32x4*)&msgL[1][nl][cc * 4];
      f32x4 mc = *(const f32x4*)&msgL[2][nl][cc * 4];
      f32x4 md = *(const f32x4*)&msgL[3][nl][cc * 4];
      f32x4 m4 = ma + mb + mc + md;
      s[0] += wcr[cc * 4 + 0] * m4[0];
      s[1] += wcr[cc * 4 + 1] * m4[1];
      s[2] += wcr[cc * 4 + 2] * m4[2];
      s[3] += wcr[cc * 4 + 3] * m4[3];
    }
    const size_t idx = ((size_t)b * NN + n0 + nl) * 32 + o;
    const float val = s[0] + s[1] + s[2] + s[3] + bcv + ldel(graph, idx, f32m);
    if (f32m) ((float*)outv)[idx] = val;
    else      ((short*)outv)[idx] = f2bf(val);
  }
}

// ---------------------------------------------------------------------------
extern "C" void kernel_launch(void* const* d_in, const int* in_sizes, int n_in,
                              void* d_out, int out_size, void* d_ws, size_t ws_size,
                              hipStream_t stream) {
  const void* graph = d_in[0];
  const void* img   = d_in[1];
  const void* Wq    = d_in[2];
  const void* bq    = d_in[3];
  const void* Wk    = d_in[4];
  const void* bk    = d_in[5];
  const void* Wv    = d_in[6];
  const void* bv    = d_in[7];
  const void* Wc    = d_in[8];
  const void* bc    = d_in[9];
  char* ws = (char*)d_ws;
  short*    Qb  = (short*)(ws + 0);          // 2 MB  bf16 [B][N][32]
  short*    Kt  = (short*)(ws + 2097152);    // 2 MB  bf16 [B][L][32] (scaled)
  _Float16* Vt  = (_Float16*)(ws + 4194304); // 2 MB  f16  [B][L][32]
  _Float16* Vpp = (_Float16*)(ws + 6291456); // 2 MB  f16  [B][32][L] (V*4096/Z)
  ka_proj<<<dim3(1024), dim3(256), 0, stream>>>(graph, img, Wq, bq, Wk, bk, Wv, bv,
                                                Qb, Kt, Vt);
  kb_z<<<dim3(512), dim3(256), 0, stream>>>(Qb, Kt, Vt, Vpp);
  kc_attn<<<dim3(1024), dim3(256), 0, stream>>>(Qb, Kt, Vpp, graph, Wc, bc, d_out);
}

// Round 4
// 209.152 us; speedup vs baseline: 1.0442x; 1.0442x over previous
//
#include <hip/hip_runtime.h>

#define BB 8
#define NN 4096
#define LL 4096
#define CC 256

typedef short bf16x8 __attribute__((ext_vector_type(8)));
typedef _Float16 f16x8 __attribute__((ext_vector_type(8)));
typedef _Float16 f16x2 __attribute__((ext_vector_type(2)));
typedef __fp16 hf16x2 __attribute__((ext_vector_type(2)));  // cvt_pkrtz return type
typedef float f32x4 __attribute__((ext_vector_type(4)));

__device__ __forceinline__ short f2bf(float f) {
  union { float f; unsigned u; } v; v.f = f;
  unsigned r = v.u + 0x7fffu + ((v.u >> 16) & 1u);
  return (short)(r >> 16);
}
// 8 consecutive f32 -> bf16x8 MFMA fragment (two float4 loads)
__device__ __forceinline__ bf16x8 ld8(const float* __restrict__ fp) {
  float4 a = *(const float4*)fp;
  float4 b = *(const float4*)(fp + 4);
  bf16x8 r;
  r[0] = f2bf(a.x); r[1] = f2bf(a.y); r[2] = f2bf(a.z); r[3] = f2bf(a.w);
  r[4] = f2bf(b.x); r[5] = f2bf(b.y); r[6] = f2bf(b.z); r[7] = f2bf(b.w);
  return r;
}

// ---------------------------------------------------------------------------
// Kernel A: projections (inputs are f32 — proven by round-3 pass).
//   blocks 0..511   : Kt[b][l][o] = (Wk@img + bk)[o][l] * log2(e)/sqrt(32) (bf16)
//                     Vt[b][l][o] = (Wv@img + bv)[o][l]                    (f16)
//   blocks 512..1023: Qb[b][n][o] = (graph@Wq^T + bq)[n][o]                (bf16)
// ---------------------------------------------------------------------------
__global__ __launch_bounds__(256) void ka_proj(
    const float* __restrict__ graph, const float* __restrict__ img,
    const float* __restrict__ Wq, const float* __restrict__ bq,
    const float* __restrict__ Wk, const float* __restrict__ bk,
    const float* __restrict__ Wv, const float* __restrict__ bv,
    short* __restrict__ Qb, short* __restrict__ Kt, _Float16* __restrict__ Vt)
{
  const int tid = threadIdx.x;
  const int w = tid >> 6, lane = tid & 63, lo = lane & 15, q = lane >> 4;
  const int bid = blockIdx.x;
  if (bid < 512) {
    const int b = bid >> 6;
    const int lt = ((bid & 63) << 6) + (w << 4);
    f32x4 aK0 = {0,0,0,0}, aK1 = {0,0,0,0}, aV0 = {0,0,0,0}, aV1 = {0,0,0,0};
    const float* ib = img + (size_t)b * CC * LL + lt + lo;
    #pragma unroll
    for (int cs = 0; cs < 8; ++cs) {
      const int c0 = cs * 32 + q * 8;
      bf16x8 bi;
      #pragma unroll
      for (int j = 0; j < 8; ++j) bi[j] = f2bf(ib[(size_t)(c0 + j) * LL]);
      bf16x8 wk0 = ld8(Wk + lo * CC + c0);
      bf16x8 wk1 = ld8(Wk + (lo + 16) * CC + c0);
      bf16x8 wv0 = ld8(Wv + lo * CC + c0);
      bf16x8 wv1 = ld8(Wv + (lo + 16) * CC + c0);
      aK0 = __builtin_amdgcn_mfma_f32_16x16x32_bf16(wk0, bi, aK0, 0, 0, 0);
      aK1 = __builtin_amdgcn_mfma_f32_16x16x32_bf16(wk1, bi, aK1, 0, 0, 0);
      aV0 = __builtin_amdgcn_mfma_f32_16x16x32_bf16(wv0, bi, aV0, 0, 0, 0);
      aV1 = __builtin_amdgcn_mfma_f32_16x16x32_bf16(wv1, bi, aV1, 0, 0, 0);
    }
    // fold 1/sqrt(32) * log2(e) into K so softmax exp becomes a raw v_exp_f32
    const float kscale = 0.2550348663f;
    const size_t row = ((size_t)b * LL + lt + lo) * 32;
    short4 s0, s1;
    s0.x = f2bf((aK0[0] + bk[q * 4 + 0]) * kscale);
    s0.y = f2bf((aK0[1] + bk[q * 4 + 1]) * kscale);
    s0.z = f2bf((aK0[2] + bk[q * 4 + 2]) * kscale);
    s0.w = f2bf((aK0[3] + bk[q * 4 + 3]) * kscale);
    s1.x = f2bf((aK1[0] + bk[16 + q * 4 + 0]) * kscale);
    s1.y = f2bf((aK1[1] + bk[16 + q * 4 + 1]) * kscale);
    s1.z = f2bf((aK1[2] + bk[16 + q * 4 + 2]) * kscale);
    s1.w = f2bf((aK1[3] + bk[16 + q * 4 + 3]) * kscale);
    *(short4*)(Kt + row + q * 4) = s0;
    *(short4*)(Kt + row + 16 + q * 4) = s1;
    union { hf16x2 h[2]; uint2 u; } p0, p1;
    p0.h[0] = __builtin_amdgcn_cvt_pkrtz(aV0[0] + bv[q * 4 + 0], aV0[1] + bv[q * 4 + 1]);
    p0.h[1] = __builtin_amdgcn_cvt_pkrtz(aV0[2] + bv[q * 4 + 2], aV0[3] + bv[q * 4 + 3]);
    p1.h[0] = __builtin_amdgcn_cvt_pkrtz(aV1[0] + bv[16 + q * 4 + 0], aV1[1] + bv[16 + q * 4 + 1]);
    p1.h[1] = __builtin_amdgcn_cvt_pkrtz(aV1[2] + bv[16 + q * 4 + 2], aV1[3] + bv[16 + q * 4 + 3]);
    *(uint2*)(Vt + row + q * 4) = p0.u;
    *(uint2*)(Vt + row + 16 + q * 4) = p1.u;
  } else {
    const int t = bid - 512;
    const int b = t >> 6;
    const int nt = ((t & 63) << 6) + (w << 4);
    bf16x8 ag = ld8(graph + ((size_t)b * NN + nt + lo) * 32 + q * 8);
    bf16x8 w0 = ld8(Wq + lo * 32 + q * 8);
    bf16x8 w1 = ld8(Wq + (lo + 16) * 32 + q * 8);
    f32x4 z = {0,0,0,0};
    f32x4 a0 = __builtin_amdgcn_mfma_f32_16x16x32_bf16(ag, w0, z, 0, 0, 0);
    f32x4 a1 = __builtin_amdgcn_mfma_f32_16x16x32_bf16(ag, w1, z, 0, 0, 0);
    const float b0 = bq[lo], b1 = bq[lo + 16];
    #pragma unroll
    for (int r = 0; r < 4; ++r) {
      const size_t rowq = ((size_t)b * NN + nt + q * 4 + r) * 32;
      Qb[rowq + lo] = f2bf(a0[r] + b0);
      Qb[rowq + 16 + lo] = f2bf(a1[r] + b1);
    }
  }
}

// ---------------------------------------------------------------------------
// Kernel B: Z_l = sum_n exp2(S'[n][l]) via S^T recompute, then
// Vpp[b][o][l] = Vt[b][l][o] * (4096 / Z_l)  (f16).
// Block = (b, 64 l), 1024 threads = 16 waves; wave t covers n in [t*256,(t+1)*256).
// 4 waves/SIMD for latency hiding (was 2).
// ---------------------------------------------------------------------------
__global__ __launch_bounds__(1024) void kb_z(
    const short* __restrict__ Qb, const short* __restrict__ Kt,
    const _Float16* __restrict__ Vt, _Float16* __restrict__ Vpp)
{
  __shared__ float zpart[16][64];
  __shared__ float zinv[64];
  const int tid = threadIdx.x;
  const int w = tid >> 6, lane = tid & 63, lo = lane & 15, q = lane >> 4;
  const int b = blockIdx.x >> 6;
  const int l0 = (blockIdx.x & 63) << 6;
  bf16x8 kf[4];
  #pragma unroll
  for (int f = 0; f < 4; ++f)
    kf[f] = *(const bf16x8*)(Kt + ((size_t)b * LL + l0 + f * 16 + lo) * 32 + q * 8);
  float za[4][4] = {{0}};
  const short* qbase = Qb + ((size_t)b * NN + w * 256 + lo) * 32 + q * 8;
  for (int it = 0; it < 16; ++it) {
    bf16x8 qf = *(const bf16x8*)(qbase + it * 512);
    #pragma unroll
    for (int f = 0; f < 4; ++f) {
      f32x4 z = {0,0,0,0};
      f32x4 c = __builtin_amdgcn_mfma_f32_16x16x32_bf16(kf[f], qf, z, 0, 0, 0);
      #pragma unroll
      for (int r = 0; r < 4; ++r) za[f][r] += __builtin_amdgcn_exp2f(c[r]);
    }
  }
  #pragma unroll
  for (int m = 1; m < 16; m <<= 1)
    #pragma unroll
    for (int f = 0; f < 4; ++f)
      #pragma unroll
      for (int r = 0; r < 4; ++r)
        za[f][r] += __shfl_xor(za[f][r], m, 64);
  if (lo == 0) {
    #pragma unroll
    for (int f = 0; f < 4; ++f)
      #pragma unroll
      for (int r = 0; r < 4; ++r)
        zpart[w][f * 16 + q * 4 + r] = za[f][r];
  }
  __syncthreads();
  if (tid < 64) {
    float z = 0.f;
    #pragma unroll
    for (int t = 0; t < 16; ++t) z += zpart[t][tid];
    zinv[tid] = 4096.0f / z;   // 4096: keep f16 V'' away from subnormals
  }
  __syncthreads();
  {
    const int l = tid & 63, og = tid >> 6;   // og in [0,16): 2 o's each
    const float inv = zinv[l];
    const f16x2 vv = *(const f16x2*)(Vt + ((size_t)b * LL + l0 + l) * 32 + og * 2);
    Vpp[((size_t)b * 32 + og * 2 + 0) * LL + l0 + l] = (_Float16)((float)vv[0] * inv);
    Vpp[((size_t)b * 32 + og * 2 + 1) * LL + l0 + l] = (_Float16)((float)vv[1] * inv);
  }
}

// ---------------------------------------------------------------------------
// Kernel C: pass 2.  Block = (b, 32 n); wave w covers l-quarter [w*1024,(w+1)*1024).
// Per 64-l chunk (no barrier — per-wave LDS regions):
//   S^T tiles (mfma bf16) -> v_exp_f32 -> pkrtz f16 -> LDS [n][l] -> A-frags
//   -> message mfma f16 with direct-load V'' B-frags.
// Epilogue: block-reduce msg partials, out = graph + bc + Wc@msg/4096.
// ---------------------------------------------------------------------------
__global__ __launch_bounds__(256) void kc_attn(
    const short* __restrict__ Qb, const short* __restrict__ Kt,
    const _Float16* __restrict__ Vpp, const float* __restrict__ graph,
    const float* __restrict__ Wc, const float* __restrict__ bc,
    float* __restrict__ out)
{
  __shared__ __align__(16) _Float16 P[4][32][72];   // per-wave [32 n][64 l]
  __shared__ __align__(16) float msgL[4][32][36];   // per-wave msg partial
  const int tid = threadIdx.x;
  const int w = tid >> 6, lane = tid & 63, lo = lane & 15, q = lane >> 4;
  const int b = blockIdx.x >> 7;
  const int n0 = (blockIdx.x & 127) << 5;
  const bf16x8 qf0 = *(const bf16x8*)(Qb + ((size_t)b * NN + n0 + lo) * 32 + q * 8);
  const bf16x8 qf1 = *(const bf16x8*)(Qb + ((size_t)b * NN + n0 + 16 + lo) * 32 + q * 8);
  f32x4 m00 = {0,0,0,0}, m01 = {0,0,0,0}, m10 = {0,0,0,0}, m11 = {0,0,0,0};
  const short* ktb = Kt + (size_t)b * LL * 32 + lo * 32 + q * 8;
  const _Float16* vb0 = Vpp + ((size_t)b * 32 + lo) * LL;
  const _Float16* vb1 = vb0 + (size_t)16 * LL;
  for (int lc = w * 16; lc < w * 16 + 16; ++lc) {
    const int lbase = lc * 64;
    #pragma unroll
    for (int f = 0; f < 4; ++f) {
      bf16x8 kf = *(const bf16x8*)(ktb + (size_t)(lbase + f * 16) * 32);
      f32x4 z = {0,0,0,0};
      f32x4 c0 = __builtin_amdgcn_mfma_f32_16x16x32_bf16(kf, qf0, z, 0, 0, 0);
      f32x4 c1 = __builtin_amdgcn_mfma_f32_16x16x32_bf16(kf, qf1, z, 0, 0, 0);
      union { hf16x2 h[2]; uint2 u; } pk0, pk1;
      pk0.h[0] = __builtin_amdgcn_cvt_pkrtz(__builtin_amdgcn_exp2f(c0[0]),
                                            __builtin_amdgcn_exp2f(c0[1]));
      pk0.h[1] = __builtin_amdgcn_cvt_pkrtz(__builtin_amdgcn_exp2f(c0[2]),
                                            __builtin_amdgcn_exp2f(c0[3]));
      pk1.h[0] = __builtin_amdgcn_cvt_pkrtz(__builtin_amdgcn_exp2f(c1[0]),
                                            __builtin_amdgcn_exp2f(c1[1]));
      pk1.h[1] = __builtin_amdgcn_cvt_pkrtz(__builtin_amdgcn_exp2f(c1[2]),
                                            __builtin_amdgcn_exp2f(c1[3]));
      *(uint2*)&P[w][lo][f * 16 + q * 4] = pk0.u;
      *(uint2*)&P[w][16 + lo][f * 16 + q * 4] = pk1.u;
    }
    #pragma unroll
    for (int k = 0; k < 2; ++k) {
      f16x8 pa0 = *(const f16x8*)&P[w][lo][k * 32 + q * 8];
      f16x8 pa1 = *(const f16x8*)&P[w][16 + lo][k * 32 + q * 8];
      f16x8 v0 = *(const f16x8*)(vb0 + lbase + k * 32 + q * 8);
      f16x8 v1 = *(const f16x8*)(vb1 + lbase + k * 32 + q * 8);
      m00 = __builtin_amdgcn_mfma_f32_16x16x32_f16(pa0, v0, m00, 0, 0, 0);
      m01 = __builtin_amdgcn_mfma_f32_16x16x32_f16(pa0, v1, m01, 0, 0, 0);
      m10 = __builtin_amdgcn_mfma_f32_16x16x32_f16(pa1, v0, m10, 0, 0, 0);
      m11 = __builtin_amdgcn_mfma_f32_16x16x32_f16(pa1, v1, m11, 0, 0, 0);
    }
  }
  #pragma unroll
  for (int r = 0; r < 4; ++r) {
    msgL[w][q * 4 + r][lo] = m00[r];
    msgL[w][q * 4 + r][16 + lo] = m01[r];
    msgL[w][16 + q * 4 + r][lo] = m10[r];
    msgL[w][16 + q * 4 + r][16 + lo] = m11[r];
  }
  __syncthreads();
  // epilogue: out[n][o] = graph + bc[o] + sum_c Wc[o][c]*msg[n][c] / 4096
  const int o = lane & 31, nh = lane >> 5;
  float wcr[32];
  #pragma unroll
  for (int c4 = 0; c4 < 8; ++c4) {
    float4 wc4 = *(const float4*)(Wc + o * 32 + c4 * 4);
    wcr[c4 * 4 + 0] = wc4.x * (1.0f / 4096.0f);
    wcr[c4 * 4 + 1] = wc4.y * (1.0f / 4096.0f);
    wcr[c4 * 4 + 2] = wc4.z * (1.0f / 4096.0f);
    wcr[c4 * 4 + 3] = wc4.w * (1.0f / 4096.0f);
  }
  const float bcv = bc[o];
  #pragma unroll
  for (int rr = 0; rr < 4; ++rr) {
    const int nl = w * 8 + nh * 4 + rr;
    f32x4 s = {0,0,0,0};
    #pragma unroll
    for (int cc = 0; cc < 8; ++cc) {
      f32x4 ma = *(const f32x4*)&msgL[0][nl][cc * 4];
      f32x4 mb = *(const f32x4*)&msgL[1][nl][cc * 4];
      f32x4 mc = *(const f32x4*)&msgL[2][nl][cc * 4];
      f32x4 md = *(const f32x4*)&msgL[3][nl][cc * 4];
      f32x4 m4 = ma + mb + mc + md;
      s[0] += wcr[cc * 4 + 0] * m4[0];
      s[1] += wcr[cc * 4 + 1] * m4[1];
      s[2] += wcr[cc * 4 + 2] * m4[2];
      s[3] += wcr[cc * 4 + 3] * m4[3];
    }
    const size_t idx = ((size_t)b * NN + n0 + nl) * 32 + o;
    out[idx] = s[0] + s[1] + s[2] + s[3] + bcv + graph[idx];
  }
}

// ---------------------------------------------------------------------------
extern "C" void kernel_launch(void* const* d_in, const int* in_sizes, int n_in,
                              void* d_out, int out_size, void* d_ws, size_t ws_size,
                              hipStream_t stream) {
  const float* graph = (const float*)d_in[0];
  const float* img   = (const float*)d_in[1];
  const float* Wq    = (const float*)d_in[2];
  const float* bq    = (const float*)d_in[3];
  const float* Wk    = (const float*)d_in[4];
  const float* bk    = (const float*)d_in[5];
  const float* Wv    = (const float*)d_in[6];
  const float* bv    = (const float*)d_in[7];
  const float* Wc    = (const float*)d_in[8];
  const float* bc    = (const float*)d_in[9];
  char* ws = (char*)d_ws;
  short*    Qb  = (short*)(ws + 0);          // 2 MB  bf16 [B][N][32]
  short*    Kt  = (short*)(ws + 2097152);    // 2 MB  bf16 [B][L][32] (scaled)
  _Float16* Vt  = (_Float16*)(ws + 4194304); // 2 MB  f16  [B][L][32]
  _Float16* Vpp = (_Float16*)(ws + 6291456); // 2 MB  f16  [B][32][L] (V*4096/Z)
  ka_proj<<<dim3(1024), dim3(256), 0, stream>>>(graph, img, Wq, bq, Wk, bk, Wv, bv,
                                                Qb, Kt, Vt);
  kb_z<<<dim3(512), dim3(1024), 0, stream>>>(Qb, Kt, Vt, Vpp);
  kc_attn<<<dim3(1024), dim3(256), 0, stream>>>(Qb, Kt, Vpp, graph, Wc, bc,
                                                (float*)d_out);
}

// Round 5
// 183.124 us; speedup vs baseline: 1.1926x; 1.1421x over previous
//
#include <hip/hip_runtime.h>

#define BB 8
#define NN 4096
#define LL 4096
#define CC 256

typedef short bf16x8 __attribute__((ext_vector_type(8)));
typedef _Float16 f16x8 __attribute__((ext_vector_type(8)));
typedef __fp16 hf16x2 __attribute__((ext_vector_type(2)));  // cvt_pkrtz return type
typedef float f32x4 __attribute__((ext_vector_type(4)));

__device__ __forceinline__ short f2bf(float f) {
  union { float f; unsigned u; } v; v.f = f;
  unsigned r = v.u + 0x7fffu + ((v.u >> 16) & 1u);
  return (short)(r >> 16);
}
// 8 consecutive f32 -> bf16x8 MFMA fragment (two float4 loads)
__device__ __forceinline__ bf16x8 ld8(const float* __restrict__ fp) {
  float4 a = *(const float4*)fp;
  float4 b = *(const float4*)(fp + 4);
  bf16x8 r;
  r[0] = f2bf(a.x); r[1] = f2bf(a.y); r[2] = f2bf(a.z); r[3] = f2bf(a.w);
  r[4] = f2bf(b.x); r[5] = f2bf(b.y); r[6] = f2bf(b.z); r[7] = f2bf(b.w);
  return r;
}

// ---------------------------------------------------------------------------
// Kernel A: projections (f32 inputs).  Also zeroes Zbuf (used by kb1 atomics;
// stream order guarantees completion before kb1 starts).
//   blocks 0..511   : Kt[b][l][o] = (Wk@img + bk)[o][l] * log2(e)/sqrt(32) (bf16)
//                     Vt[b][l][o] = (Wv@img + bv)[o][l]                    (f16)
//   blocks 512..1023: Qb[b][n][o] = (graph@Wq^T + bq)[n][o]                (bf16)
// ---------------------------------------------------------------------------
__global__ __launch_bounds__(256) void ka_proj(
    const float* __restrict__ graph, const float* __restrict__ img,
    const float* __restrict__ Wq, const float* __restrict__ bq,
    const float* __restrict__ Wk, const float* __restrict__ bk,
    const float* __restrict__ Wv, const float* __restrict__ bv,
    short* __restrict__ Qb, short* __restrict__ Kt, _Float16* __restrict__ Vt,
    float* __restrict__ Zbuf)
{
  const int tid = threadIdx.x;
  const int w = tid >> 6, lane = tid & 63, lo = lane & 15, q = lane >> 4;
  const int bid = blockIdx.x;
  if (bid < 512) {
    const int b = bid >> 6;
    if (tid < 64) Zbuf[(size_t)b * LL + ((bid & 63) << 6) + tid] = 0.0f;
    const int lt = ((bid & 63) << 6) + (w << 4);
    f32x4 aK0 = {0,0,0,0}, aK1 = {0,0,0,0}, aV0 = {0,0,0,0}, aV1 = {0,0,0,0};
    const float* ib = img + (size_t)b * CC * LL + lt + lo;
    #pragma unroll
    for (int cs = 0; cs < 8; ++cs) {
      const int c0 = cs * 32 + q * 8;
      bf16x8 bi;
      #pragma unroll
      for (int j = 0; j < 8; ++j) bi[j] = f2bf(ib[(size_t)(c0 + j) * LL]);
      bf16x8 wk0 = ld8(Wk + lo * CC + c0);
      bf16x8 wk1 = ld8(Wk + (lo + 16) * CC + c0);
      bf16x8 wv0 = ld8(Wv + lo * CC + c0);
      bf16x8 wv1 = ld8(Wv + (lo + 16) * CC + c0);
      aK0 = __builtin_amdgcn_mfma_f32_16x16x32_bf16(wk0, bi, aK0, 0, 0, 0);
      aK1 = __builtin_amdgcn_mfma_f32_16x16x32_bf16(wk1, bi, aK1, 0, 0, 0);
      aV0 = __builtin_amdgcn_mfma_f32_16x16x32_bf16(wv0, bi, aV0, 0, 0, 0);
      aV1 = __builtin_amdgcn_mfma_f32_16x16x32_bf16(wv1, bi, aV1, 0, 0, 0);
    }
    // fold 1/sqrt(32) * log2(e) into K so softmax exp becomes a raw v_exp_f32
    const float kscale = 0.2550348663f;
    const size_t row = ((size_t)b * LL + lt + lo) * 32;
    short4 s0, s1;
    s0.x = f2bf((aK0[0] + bk[q * 4 + 0]) * kscale);
    s0.y = f2bf((aK0[1] + bk[q * 4 + 1]) * kscale);
    s0.z = f2bf((aK0[2] + bk[q * 4 + 2]) * kscale);
    s0.w = f2bf((aK0[3] + bk[q * 4 + 3]) * kscale);
    s1.x = f2bf((aK1[0] + bk[16 + q * 4 + 0]) * kscale);
    s1.y = f2bf((aK1[1] + bk[16 + q * 4 + 1]) * kscale);
    s1.z = f2bf((aK1[2] + bk[16 + q * 4 + 2]) * kscale);
    s1.w = f2bf((aK1[3] + bk[16 + q * 4 + 3]) * kscale);
    *(short4*)(Kt + row + q * 4) = s0;
    *(short4*)(Kt + row + 16 + q * 4) = s1;
    union { hf16x2 h[2]; uint2 u; } p0, p1;
    p0.h[0] = __builtin_amdgcn_cvt_pkrtz(aV0[0] + bv[q * 4 + 0], aV0[1] + bv[q * 4 + 1]);
    p0.h[1] = __builtin_amdgcn_cvt_pkrtz(aV0[2] + bv[q * 4 + 2], aV0[3] + bv[q * 4 + 3]);
    p1.h[0] = __builtin_amdgcn_cvt_pkrtz(aV1[0] + bv[16 + q * 4 + 0], aV1[1] + bv[16 + q * 4 + 1]);
    p1.h[1] = __builtin_amdgcn_cvt_pkrtz(aV1[2] + bv[16 + q * 4 + 2], aV1[3] + bv[16 + q * 4 + 3]);
    *(uint2*)(Vt + row + q * 4) = p0.u;
    *(uint2*)(Vt + row + 16 + q * 4) = p1.u;
  } else {
    const int t = bid - 512;
    const int b = t >> 6;
    const int nt = ((t & 63) << 6) + (w << 4);
    bf16x8 ag = ld8(graph + ((size_t)b * NN + nt + lo) * 32 + q * 8);
    bf16x8 w0 = ld8(Wq + lo * 32 + q * 8);
    bf16x8 w1 = ld8(Wq + (lo + 16) * 32 + q * 8);
    f32x4 z = {0,0,0,0};
    f32x4 a0 = __builtin_amdgcn_mfma_f32_16x16x32_bf16(ag, w0, z, 0, 0, 0);
    f32x4 a1 = __builtin_amdgcn_mfma_f32_16x16x32_bf16(ag, w1, z, 0, 0, 0);
    const float b0 = bq[lo], b1 = bq[lo + 16];
    #pragma unroll
    for (int r = 0; r < 4; ++r) {
      const size_t rowq = ((size_t)b * NN + nt + q * 4 + r) * 32;
      Qb[rowq + lo] = f2bf(a0[r] + b0);
      Qb[rowq + 16 + lo] = f2bf(a1[r] + b1);
    }
  }
}

// ---------------------------------------------------------------------------
// Kernel B1: partial softmax denominators.  Grid = 8b x 64 ltile x 4 nq =
// 2048 blocks x 4 waves (8 blocks/CU -> 32 waves/CU).  Wave w: 64 l x 256 n.
// Z[b][l] += sum_n exp2(S'[l][n]) via device-scope atomicAdd (Zbuf zeroed in ka).
// ---------------------------------------------------------------------------
__global__ __launch_bounds__(256) void kb1_z(
    const short* __restrict__ Qb, const short* __restrict__ Kt,
    float* __restrict__ Z)
{
  const int tid = threadIdx.x;
  const int w = tid >> 6, lane = tid & 63, lo = lane & 15, q = lane >> 4;
  const int bid = blockIdx.x;
  const int b = bid >> 8;
  const int l0 = ((bid >> 2) & 63) << 6;
  const int nq = bid & 3;
  bf16x8 kf[4];
  #pragma unroll
  for (int f = 0; f < 4; ++f)
    kf[f] = *(const bf16x8*)(Kt + ((size_t)b * LL + l0 + f * 16 + lo) * 32 + q * 8);
  float za[4][4] = {{0}};
  const short* qbase = Qb + ((size_t)b * NN + nq * 1024 + w * 256 + lo) * 32 + q * 8;
  #pragma unroll 4
  for (int it = 0; it < 16; ++it) {
    bf16x8 qf = *(const bf16x8*)(qbase + it * 512);
    #pragma unroll
    for (int f = 0; f < 4; ++f) {
      f32x4 z = {0,0,0,0};
      f32x4 c = __builtin_amdgcn_mfma_f32_16x16x32_bf16(kf[f], qf, z, 0, 0, 0);
      #pragma unroll
      for (int r = 0; r < 4; ++r) za[f][r] += __builtin_amdgcn_exp2f(c[r]);
    }
  }
  // reduce over n (= lo, low 4 lane bits)
  #pragma unroll
  for (int m = 1; m < 16; m <<= 1)
    #pragma unroll
    for (int f = 0; f < 4; ++f)
      #pragma unroll
      for (int r = 0; r < 4; ++r)
        za[f][r] += __shfl_xor(za[f][r], m, 64);
  if (lo == 0) {
    #pragma unroll
    for (int f = 0; f < 4; ++f)
      #pragma unroll
      for (int r = 0; r < 4; ++r)
        atomicAdd(&Z[(size_t)b * LL + l0 + f * 16 + q * 4 + r], za[f][r]);
  }
}

// ---------------------------------------------------------------------------
// Kernel B2: Vpp[b][o][l] = Vt[b][l][o] * (4096 / Z_l)  (f16, [o][l] layout).
// 512 blocks x 256 threads; thread: one l, 8 o's.
// ---------------------------------------------------------------------------
__global__ __launch_bounds__(256) void kb2_scale(
    const _Float16* __restrict__ Vt, const float* __restrict__ Z,
    _Float16* __restrict__ Vpp)
{
  const int tid = threadIdx.x;
  const int b = blockIdx.x >> 6;
  const int l = ((blockIdx.x & 63) << 6) + (tid & 63);
  const int og = tid >> 6;  // 0..3
  const float inv = __builtin_amdgcn_rcpf(Z[(size_t)b * LL + l]) * 4096.0f;
  const f16x8 vv = *(const f16x8*)(Vt + ((size_t)b * LL + l) * 32 + og * 8);
  #pragma unroll
  for (int j = 0; j < 8; ++j)
    Vpp[((size_t)b * 32 + og * 8 + j) * LL + l] = (_Float16)((float)vv[j] * inv);
}

// ---------------------------------------------------------------------------
// Kernel C: pass 2.  Block = (b, 32 n); wave w covers l in [w*1024,(w+1)*1024).
// Software-pipelined: Kt frags prefetched one lc ahead; V frags hoisted above
// the exp2/f-loop.  P(LDS) and msg-partial LDS share one 18.4 KB region
// (msg written only after the wave's final P read; per-wave regions).
// ---------------------------------------------------------------------------
__global__ __launch_bounds__(256) void kc_attn(
    const short* __restrict__ Qb, const short* __restrict__ Kt,
    const _Float16* __restrict__ Vpp, const float* __restrict__ graph,
    const float* __restrict__ Wc, const float* __restrict__ bc,
    float* __restrict__ out)
{
  __shared__ __align__(16) unsigned char smem[4 * 32 * 72 * 2];  // 18432 B
  const int tid = threadIdx.x;
  const int w = tid >> 6, lane = tid & 63, lo = lane & 15, q = lane >> 4;
  const int b = blockIdx.x >> 7;
  const int n0 = (blockIdx.x & 127) << 5;
  _Float16* Pw = (_Float16*)smem + w * (32 * 72);     // [32 n][72]
  float* MS = (float*)smem;                           // [4][32][36] (post-loop)
  const bf16x8 qf0 = *(const bf16x8*)(Qb + ((size_t)b * NN + n0 + lo) * 32 + q * 8);
  const bf16x8 qf1 = *(const bf16x8*)(Qb + ((size_t)b * NN + n0 + 16 + lo) * 32 + q * 8);
  f32x4 m00 = {0,0,0,0}, m01 = {0,0,0,0}, m10 = {0,0,0,0}, m11 = {0,0,0,0};
  const short* ktb = Kt + (size_t)b * LL * 32 + lo * 32 + q * 8;
  const _Float16* vb0 = Vpp + ((size_t)b * 32 + lo) * LL;
  const _Float16* vb1 = vb0 + (size_t)16 * LL;
  const int lc0 = w * 16;
  bf16x8 kfN[4];
  #pragma unroll
  for (int f = 0; f < 4; ++f)
    kfN[f] = *(const bf16x8*)(ktb + (size_t)(lc0 * 64 + f * 16) * 32);
  for (int lc = lc0; lc < lc0 + 16; ++lc) {
    const int lbase = lc * 64;
    bf16x8 kfC[4];
    #pragma unroll
    for (int f = 0; f < 4; ++f) kfC[f] = kfN[f];
    // V frags for this lc (consumed ~200cy later in the k-loop)
    f16x8 vA0 = *(const f16x8*)(vb0 + lbase + q * 8);
    f16x8 vA1 = *(const f16x8*)(vb0 + lbase + 32 + q * 8);
    f16x8 vB0 = *(const f16x8*)(vb1 + lbase + q * 8);
    f16x8 vB1 = *(const f16x8*)(vb1 + lbase + 32 + q * 8);
    // prefetch next-lc Kt frags (clamped, branchless)
    const int lcn = (lc + 1 < lc0 + 16) ? lc + 1 : lc;
    #pragma unroll
    for (int f = 0; f < 4; ++f)
      kfN[f] = *(const bf16x8*)(ktb + (size_t)(lcn * 64 + f * 16) * 32);
    #pragma unroll
    for (int f = 0; f < 4; ++f) {
      f32x4 z = {0,0,0,0};
      f32x4 c0 = __builtin_amdgcn_mfma_f32_16x16x32_bf16(kfC[f], qf0, z, 0, 0, 0);
      f32x4 c1 = __builtin_amdgcn_mfma_f32_16x16x32_bf16(kfC[f], qf1, z, 0, 0, 0);
      union { hf16x2 h[2]; uint2 u; } pk0, pk1;
      pk0.h[0] = __builtin_amdgcn_cvt_pkrtz(__builtin_amdgcn_exp2f(c0[0]),
                                            __builtin_amdgcn_exp2f(c0[1]));
      pk0.h[1] = __builtin_amdgcn_cvt_pkrtz(__builtin_amdgcn_exp2f(c0[2]),
                                            __builtin_amdgcn_exp2f(c0[3]));
      pk1.h[0] = __builtin_amdgcn_cvt_pkrtz(__builtin_amdgcn_exp2f(c1[0]),
                                            __builtin_amdgcn_exp2f(c1[1]));
      pk1.h[1] = __builtin_amdgcn_cvt_pkrtz(__builtin_amdgcn_exp2f(c1[2]),
                                            __builtin_amdgcn_exp2f(c1[3]));
      *(uint2*)&Pw[lo * 72 + f * 16 + q * 4] = pk0.u;
      *(uint2*)&Pw[(16 + lo) * 72 + f * 16 + q * 4] = pk1.u;
    }
    {
      f16x8 pa00 = *(const f16x8*)&Pw[lo * 72 + q * 8];
      f16x8 pa01 = *(const f16x8*)&Pw[lo * 72 + 32 + q * 8];
      f16x8 pa10 = *(const f16x8*)&Pw[(16 + lo) * 72 + q * 8];
      f16x8 pa11 = *(const f16x8*)&Pw[(16 + lo) * 72 + 32 + q * 8];
      m00 = __builtin_amdgcn_mfma_f32_16x16x32_f16(pa00, vA0, m00, 0, 0, 0);
      m10 = __builtin_amdgcn_mfma_f32_16x16x32_f16(pa10, vA0, m10, 0, 0, 0);
      m01 = __builtin_amdgcn_mfma_f32_16x16x32_f16(pa00, vB0, m01, 0, 0, 0);
      m11 = __builtin_amdgcn_mfma_f32_16x16x32_f16(pa10, vB0, m11, 0, 0, 0);
      m00 = __builtin_amdgcn_mfma_f32_16x16x32_f16(pa01, vA1, m00, 0, 0, 0);
      m10 = __builtin_amdgcn_mfma_f32_16x16x32_f16(pa11, vA1, m10, 0, 0, 0);
      m01 = __builtin_amdgcn_mfma_f32_16x16x32_f16(pa01, vB1, m01, 0, 0, 0);
      m11 = __builtin_amdgcn_mfma_f32_16x16x32_f16(pa11, vB1, m11, 0, 0, 0);
    }
  }
  // stash msg partials into the SAME LDS region (all P reads for this wave done)
  float* MSw = MS + w * (32 * 36);
  #pragma unroll
  for (int r = 0; r < 4; ++r) {
    MSw[(q * 4 + r) * 36 + lo] = m00[r];
    MSw[(q * 4 + r) * 36 + 16 + lo] = m01[r];
    MSw[(16 + q * 4 + r) * 36 + lo] = m10[r];
    MSw[(16 + q * 4 + r) * 36 + 16 + lo] = m11[r];
  }
  __syncthreads();
  // epilogue: out[n][o] = graph + bc[o] + sum_c Wc[o][c]*msg[n][c] / 4096
  const int o = lane & 31, nh = lane >> 5;
  float wcr[32];
  #pragma unroll
  for (int c4 = 0; c4 < 8; ++c4) {
    float4 wc4 = *(const float4*)(Wc + o * 32 + c4 * 4);
    wcr[c4 * 4 + 0] = wc4.x * (1.0f / 4096.0f);
    wcr[c4 * 4 + 1] = wc4.y * (1.0f / 4096.0f);
    wcr[c4 * 4 + 2] = wc4.z * (1.0f / 4096.0f);
    wcr[c4 * 4 + 3] = wc4.w * (1.0f / 4096.0f);
  }
  const float bcv = bc[o];
  #pragma unroll
  for (int rr = 0; rr < 4; ++rr) {
    const int nl = w * 8 + nh * 4 + rr;
    f32x4 s = {0,0,0,0};
    #pragma unroll
    for (int cc = 0; cc < 8; ++cc) {
      f32x4 ma = *(const f32x4*)&MS[0 * 1152 + nl * 36 + cc * 4];
      f32x4 mb = *(const f32x4*)&MS[1 * 1152 + nl * 36 + cc * 4];
      f32x4 mc = *(const f32x4*)&MS[2 * 1152 + nl * 36 + cc * 4];
      f32x4 md = *(const f32x4*)&MS[3 * 1152 + nl * 36 + cc * 4];
      f32x4 m4 = ma + mb + mc + md;
      s[0] += wcr[cc * 4 + 0] * m4[0];
      s[1] += wcr[cc * 4 + 1] * m4[1];
      s[2] += wcr[cc * 4 + 2] * m4[2];
      s[3] += wcr[cc * 4 + 3] * m4[3];
    }
    const size_t idx = ((size_t)b * NN + n0 + nl) * 32 + o;
    out[idx] = s[0] + s[1] + s[2] + s[3] + bcv + graph[idx];
  }
}

// ---------------------------------------------------------------------------
extern "C" void kernel_launch(void* const* d_in, const int* in_sizes, int n_in,
                              void* d_out, int out_size, void* d_ws, size_t ws_size,
                              hipStream_t stream) {
  const float* graph = (const float*)d_in[0];
  const float* img   = (const float*)d_in[1];
  const float* Wq    = (const float*)d_in[2];
  const float* bq    = (const float*)d_in[3];
  const float* Wk    = (const float*)d_in[4];
  const float* bk    = (const float*)d_in[5];
  const float* Wv    = (const float*)d_in[6];
  const float* bv    = (const float*)d_in[7];
  const float* Wc    = (const float*)d_in[8];
  const float* bc    = (const float*)d_in[9];
  char* ws = (char*)d_ws;
  short*    Qb  = (short*)(ws + 0);          // 2 MB   bf16 [B][N][32]
  short*    Kt  = (short*)(ws + 2097152);    // 2 MB   bf16 [B][L][32] (scaled)
  _Float16* Vt  = (_Float16*)(ws + 4194304); // 2 MB   f16  [B][L][32]
  _Float16* Vpp = (_Float16*)(ws + 6291456); // 2 MB   f16  [B][32][L] (V*4096/Z)
  float*    Zb  = (float*)(ws + 8388608);    // 128 KB f32  [B][L]
  ka_proj<<<dim3(1024), dim3(256), 0, stream>>>(graph, img, Wq, bq, Wk, bk, Wv, bv,
                                                Qb, Kt, Vt, Zb);
  kb1_z<<<dim3(2048), dim3(256), 0, stream>>>(Qb, Kt, Zb);
  kb2_scale<<<dim3(512), dim3(256), 0, stream>>>(Vt, Zb, Vpp);
  kc_attn<<<dim3(1024), dim3(256), 0, stream>>>(Qb, Kt, Vpp, graph, Wc, bc,
                                                (float*)d_out);
}